// Round 10
// baseline (16.243 us; speedup 1.0000x reference)
//
#include <hip/hip_runtime.h>
#include <math.h>

// PolyIoULoss closed-form, two-kernel structure (FINAL structure).
// Fusion post-mortems: R4 (release atomics) 73us, R7 (relaxed+single counter)
// 21us, R8 (hierarchical int tree, <=64 contenders) 22us — vs 12.6us for two
// plain dispatches. Do not re-fuse.
// R9 post-mortem: float2 paired loads regressed (14.7us) — second pair's 20
// values live across the whole first pair body; scalar loads at point of use
// schedule better. One lever per round near plateau.
//
// Area(P∩T) via Green's theorem: each clipped edge contributes
// (t1-t0)*cross(A,r); cross(A,r) collapses to per-box constants plus offset
// corrections (components of R(psi)*tc). t0/t1 via Liang-Barsky against an
// AABB in the other box's local frame. Branchless; IEEE inf handles parallel
// edges. ITEMS=4 (512 blocks) — measured best (R5: 12.61us).
// This round: R5 kernel1 verbatim + single-wave shuffle-only reduce
// (isolated A/B of the reduce tail).

#define BS 256
#define ITEMS 4

__device__ __forceinline__ float lb_delta(float Ax, float Ay,
                                          float irx, float iry,
                                          float hw, float hh)
{
    // Liang-Barsky span of segment A + t*r, t in [0,1], vs |x|<=hw,|y|<=hh
    const float tA = (-hw - Ax) * irx;
    const float tB = ( hw - Ax) * irx;
    const float tC = (-hh - Ay) * iry;
    const float tD = ( hh - Ay) * iry;
    const float tx0 = fminf(tA, tB), tx1 = fmaxf(tA, tB);
    const float ty0 = fminf(tC, tD), ty1 = fmaxf(tC, tD);
    const float t0 = fmaxf(fmaxf(tx0, ty0), 0.0f);   // v_max3
    const float t1 = fminf(fminf(tx1, ty1), 1.0f);   // v_min3
    return fmaxf(t1 - t0, 0.0f);
}

__device__ __forceinline__ float pair_loss(const float* __restrict__ pp,
                                           const float* __restrict__ tp)
{
    const float pcx = pp[0], pcy = pp[1], pw = pp[2], ph = pp[3], phi = pp[4];
    const float tcx = tp[0] - pcx, tcy = tp[1] - pcy;   // pred-centered frame
    const float tw = tp[2], th = tp[3], psi = tp[4];

    const float a1 = 0.5f * pw, b1 = 0.5f * ph;
    const float a2 = 0.5f * tw, b2 = 0.5f * th;

    float sphi, cphi, spsi, cpsi;
    __sincosf(phi, &sphi, &cphi);
    __sincosf(psi, &spsi, &cpsi);
    // delta = psi - phi
    const float cd = cpsi * cphi + spsi * sphi;
    const float sd = spsi * cphi - cpsi * sphi;

    // ---- P edges in T-local frame; clipper AABB (a2,b2) ----
    const float Cx = cpsi * tcx - spsi * tcy;
    const float Cy = spsi * tcx + cpsi * tcy;
    const float Xx = a1 * cd,  Xy = a1 * sd;
    const float Yx = -b1 * sd, Yy = b1 * cd;
    const float i0x = __builtin_amdgcn_rcpf(2.0f * Xx);
    const float i0y = __builtin_amdgcn_rcpf(2.0f * Xy);
    const float i1x = __builtin_amdgcn_rcpf(2.0f * Yx);
    const float i1y = __builtin_amdgcn_rcpf(2.0f * Yy);

    const float dP0 = lb_delta(-Xx - Yx - Cx, -Xy - Yy - Cy,  i0x,  i0y, a2, b2);
    const float dP1 = lb_delta( Xx - Yx - Cx,  Xy - Yy - Cy,  i1x,  i1y, a2, b2);
    const float dP2 = lb_delta( Xx + Yx - Cx,  Xy + Yy - Cy, -i0x, -i0y, a2, b2);
    const float dP3 = lb_delta(-Xx + Yx - Cx, -Xy + Yy - Cy, -i1x, -i1y, a2, b2);
    const float sumP = (dP0 + dP1) + (dP2 + dP3);

    // ---- T edges in P-local frame; clipper AABB (a1,b1) ----
    const float C2x = cphi * tcx - sphi * tcy;
    const float C2y = sphi * tcx + cphi * tcy;
    const float Xpx = a2 * cd,  Xpy = -a2 * sd;
    const float Ypx = b2 * sd,  Ypy = b2 * cd;
    const float j0x = __builtin_amdgcn_rcpf(2.0f * Xpx);
    const float j0y = __builtin_amdgcn_rcpf(2.0f * Xpy);
    const float j1x = __builtin_amdgcn_rcpf(2.0f * Ypx);
    const float j1y = __builtin_amdgcn_rcpf(2.0f * Ypy);

    const float dT0 = lb_delta(C2x - Xpx - Ypx, C2y - Xpy - Ypy,  j0x,  j0y, a1, b1);
    const float dT1 = lb_delta(C2x + Xpx - Ypx, C2y + Xpy - Ypy,  j1x,  j1y, a1, b1);
    const float dT2 = lb_delta(C2x + Xpx + Ypx, C2y + Xpy + Ypy, -j0x, -j0y, a1, b1);
    const float dT3 = lb_delta(C2x - Xpx + Ypx, C2y - Xpy + Ypy, -j1x, -j1y, a1, b1);
    const float sumT = (dT0 + dT1) + (dT2 + dT3);

    float area = a1 * b1 * sumP + a2 * b2 * sumT
               - a2 * Cy * (dT0 - dT2) + b2 * Cx * (dT1 - dT3);
    area = fmaxf(area, 0.0f);

    const float A1 = pw * ph, A2 = tw * th;
    const float iou = fmaxf(area / (A1 + A2 - area + 1e-6f), 1e-6f);
    return -__logf(iou);
}

__global__ __launch_bounds__(BS) void poly_iou_kernel(
    const float* __restrict__ pred, const float* __restrict__ tgt,
    float* __restrict__ block_sums, int n)
{
    const int tid = threadIdx.x;
    const int stride = gridDim.x * BS;   // threads in grid

    float loss = 0.0f;
#pragma unroll
    for (int it = 0; it < ITEMS; ++it) {
        const int gid = blockIdx.x * BS + tid + it * stride;
        if (gid < n)
            loss += pair_loss(pred + (long)gid * 5, tgt + (long)gid * 5);
    }

    // block reduction (wave shuffle + tiny LDS), deterministic
#pragma unroll
    for (int off = 32; off > 0; off >>= 1) loss += __shfl_down(loss, off);
    __shared__ float wsum[BS / 64];
    if ((tid & 63) == 0) wsum[tid >> 6] = loss;
    __syncthreads();
    if (tid == 0) {
        float s = 0.0f;
#pragma unroll
        for (int w = 0; w < BS / 64; ++w) s += wsum[w];
        block_sums[blockIdx.x] = s;
    }
}

// Single-wave reduce: no LDS, no barriers on the dependent tail.
__global__ __launch_bounds__(64) void poly_iou_reduce(
    const float* __restrict__ block_sums, int nblocks,
    float* __restrict__ out, double inv_n)
{
    const int tid = threadIdx.x;
    double s = 0.0;
    for (int i = tid; i < nblocks; i += 64)
        s += (double)block_sums[i];
#pragma unroll
    for (int off = 32; off > 0; off >>= 1) s += __shfl_down(s, off);
    if (tid == 0) out[0] = (float)(s * inv_n);
}

extern "C" void kernel_launch(void* const* d_in, const int* in_sizes, int n_in,
                              void* d_out, int out_size, void* d_ws, size_t ws_size,
                              hipStream_t stream) {
    const float* pred = (const float*)d_in[0];
    const float* tgt  = (const float*)d_in[1];
    float* out = (float*)d_out;
    const int n = in_sizes[0] / 5;
    const int nblocks = (n + BS * ITEMS - 1) / (BS * ITEMS);
    float* bsums = (float*)d_ws;

    hipLaunchKernelGGL(poly_iou_kernel, dim3(nblocks), dim3(BS), 0, stream,
                       pred, tgt, bsums, n);
    hipLaunchKernelGGL(poly_iou_reduce, dim3(1), dim3(64), 0, stream,
                       bsums, nblocks, out, 1.0 / (double)n);
}

// Round 11
// 12.803 us; speedup vs baseline: 1.2687x; 1.2687x over previous
//
#include <hip/hip_runtime.h>
#include <math.h>

// PolyIoULoss closed-form, two-kernel structure (FINAL — R5 verbatim).
//
// Measured ledger:
//   R4 fused release-atomics: 73us   | R7 fused relaxed+counter: 21us
//   R8 fused hierarchical tree: 22us | -> two plain dispatches win. No re-fuse.
//   R5 ITEMS=4 + 256-thr reduce: 12.61us  <- best
//   R6 ITEMS=2 + 256-thr reduce: 12.79us  (occupancy insensitive)
//   R9/R10 64-thr wave reduce: 14.7/16.2us <- REGRESSION: 8 dependent
//     cross-XCD partial loads per lane serialize (~500-900cy each); the
//     256-thread reduce has 4x the load parallelism. Keep 256-thr reduce.
//
// Area(P∩T) via Green's theorem: each clipped edge contributes
// (t1-t0)*cross(A,r); cross(A,r) collapses to per-box constants plus offset
// corrections (components of R(psi)*tc). t0/t1 via Liang-Barsky against an
// AABB in the other box's local frame. Branchless; IEEE inf handles parallel
// edges. ITEMS=4 (512 blocks).

#define BS 256
#define ITEMS 4

__device__ __forceinline__ float lb_delta(float Ax, float Ay,
                                          float irx, float iry,
                                          float hw, float hh)
{
    // Liang-Barsky span of segment A + t*r, t in [0,1], vs |x|<=hw,|y|<=hh
    const float tA = (-hw - Ax) * irx;
    const float tB = ( hw - Ax) * irx;
    const float tC = (-hh - Ay) * iry;
    const float tD = ( hh - Ay) * iry;
    const float tx0 = fminf(tA, tB), tx1 = fmaxf(tA, tB);
    const float ty0 = fminf(tC, tD), ty1 = fmaxf(tC, tD);
    const float t0 = fmaxf(fmaxf(tx0, ty0), 0.0f);   // v_max3
    const float t1 = fminf(fminf(tx1, ty1), 1.0f);   // v_min3
    return fmaxf(t1 - t0, 0.0f);
}

__device__ __forceinline__ float pair_loss(const float* __restrict__ pp,
                                           const float* __restrict__ tp)
{
    const float pcx = pp[0], pcy = pp[1], pw = pp[2], ph = pp[3], phi = pp[4];
    const float tcx = tp[0] - pcx, tcy = tp[1] - pcy;   // pred-centered frame
    const float tw = tp[2], th = tp[3], psi = tp[4];

    const float a1 = 0.5f * pw, b1 = 0.5f * ph;
    const float a2 = 0.5f * tw, b2 = 0.5f * th;

    float sphi, cphi, spsi, cpsi;
    __sincosf(phi, &sphi, &cphi);
    __sincosf(psi, &spsi, &cpsi);
    // delta = psi - phi
    const float cd = cpsi * cphi + spsi * sphi;
    const float sd = spsi * cphi - cpsi * sphi;

    // ---- P edges in T-local frame; clipper AABB (a2,b2) ----
    const float Cx = cpsi * tcx - spsi * tcy;
    const float Cy = spsi * tcx + cpsi * tcy;
    const float Xx = a1 * cd,  Xy = a1 * sd;
    const float Yx = -b1 * sd, Yy = b1 * cd;
    const float i0x = __builtin_amdgcn_rcpf(2.0f * Xx);
    const float i0y = __builtin_amdgcn_rcpf(2.0f * Xy);
    const float i1x = __builtin_amdgcn_rcpf(2.0f * Yx);
    const float i1y = __builtin_amdgcn_rcpf(2.0f * Yy);

    const float dP0 = lb_delta(-Xx - Yx - Cx, -Xy - Yy - Cy,  i0x,  i0y, a2, b2);
    const float dP1 = lb_delta( Xx - Yx - Cx,  Xy - Yy - Cy,  i1x,  i1y, a2, b2);
    const float dP2 = lb_delta( Xx + Yx - Cx,  Xy + Yy - Cy, -i0x, -i0y, a2, b2);
    const float dP3 = lb_delta(-Xx + Yx - Cx, -Xy + Yy - Cy, -i1x, -i1y, a2, b2);
    const float sumP = (dP0 + dP1) + (dP2 + dP3);

    // ---- T edges in P-local frame; clipper AABB (a1,b1) ----
    const float C2x = cphi * tcx - sphi * tcy;
    const float C2y = sphi * tcx + cphi * tcy;
    const float Xpx = a2 * cd,  Xpy = -a2 * sd;
    const float Ypx = b2 * sd,  Ypy = b2 * cd;
    const float j0x = __builtin_amdgcn_rcpf(2.0f * Xpx);
    const float j0y = __builtin_amdgcn_rcpf(2.0f * Xpy);
    const float j1x = __builtin_amdgcn_rcpf(2.0f * Ypx);
    const float j1y = __builtin_amdgcn_rcpf(2.0f * Ypy);

    const float dT0 = lb_delta(C2x - Xpx - Ypx, C2y - Xpy - Ypy,  j0x,  j0y, a1, b1);
    const float dT1 = lb_delta(C2x + Xpx - Ypx, C2y + Xpy - Ypy,  j1x,  j1y, a1, b1);
    const float dT2 = lb_delta(C2x + Xpx + Ypx, C2y + Xpy + Ypy, -j0x, -j0y, a1, b1);
    const float dT3 = lb_delta(C2x - Xpx + Ypx, C2y - Xpy + Ypy, -j1x, -j1y, a1, b1);
    const float sumT = (dT0 + dT1) + (dT2 + dT3);

    float area = a1 * b1 * sumP + a2 * b2 * sumT
               - a2 * Cy * (dT0 - dT2) + b2 * Cx * (dT1 - dT3);
    area = fmaxf(area, 0.0f);

    const float A1 = pw * ph, A2 = tw * th;
    const float iou = fmaxf(area / (A1 + A2 - area + 1e-6f), 1e-6f);
    return -__logf(iou);
}

__global__ __launch_bounds__(BS) void poly_iou_kernel(
    const float* __restrict__ pred, const float* __restrict__ tgt,
    float* __restrict__ block_sums, int n)
{
    const int tid = threadIdx.x;
    const int stride = gridDim.x * BS;   // threads in grid

    float loss = 0.0f;
#pragma unroll
    for (int it = 0; it < ITEMS; ++it) {
        const int gid = blockIdx.x * BS + tid + it * stride;
        if (gid < n)
            loss += pair_loss(pred + (long)gid * 5, tgt + (long)gid * 5);
    }

    // block reduction (wave shuffle + tiny LDS), deterministic
#pragma unroll
    for (int off = 32; off > 0; off >>= 1) loss += __shfl_down(loss, off);
    __shared__ float wsum[BS / 64];
    if ((tid & 63) == 0) wsum[tid >> 6] = loss;
    __syncthreads();
    if (tid == 0) {
        float s = 0.0f;
#pragma unroll
        for (int w = 0; w < BS / 64; ++w) s += wsum[w];
        block_sums[blockIdx.x] = s;
    }
}

__global__ __launch_bounds__(BS) void poly_iou_reduce(
    const float* __restrict__ block_sums, int nblocks,
    float* __restrict__ out, double inv_n)
{
    const int tid = threadIdx.x;
    double s = 0.0;
    for (int i = tid; i < nblocks; i += BS) s += (double)block_sums[i];
#pragma unroll
    for (int off = 32; off > 0; off >>= 1) s += __shfl_down(s, off);
    __shared__ double ws[BS / 64];
    if ((tid & 63) == 0) ws[tid >> 6] = s;
    __syncthreads();
    if (tid == 0) {
        double tot = 0.0;
#pragma unroll
        for (int w = 0; w < BS / 64; ++w) tot += ws[w];
        out[0] = (float)(tot * inv_n);
    }
}

extern "C" void kernel_launch(void* const* d_in, const int* in_sizes, int n_in,
                              void* d_out, int out_size, void* d_ws, size_t ws_size,
                              hipStream_t stream) {
    const float* pred = (const float*)d_in[0];
    const float* tgt  = (const float*)d_in[1];
    float* out = (float*)d_out;
    const int n = in_sizes[0] / 5;
    const int nblocks = (n + BS * ITEMS - 1) / (BS * ITEMS);
    float* bsums = (float*)d_ws;

    hipLaunchKernelGGL(poly_iou_kernel, dim3(nblocks), dim3(BS), 0, stream,
                       pred, tgt, bsums, n);
    hipLaunchKernelGGL(poly_iou_reduce, dim3(1), dim3(BS), 0, stream,
                       bsums, nblocks, out, 1.0 / (double)n);
}

// Round 12
// 12.372 us; speedup vs baseline: 1.3129x; 1.0348x over previous
//
#include <hip/hip_runtime.h>
#include <math.h>

// PolyIoULoss closed-form, two-kernel structure.
//
// Measured ledger (2x2 decomposition solved at R11):
//   kernel1\reduce   256-thr        64-thr-wave
//   scalar loads     12.6-12.8      16.24        (R5/R6/R11, R10)
//   float2 loads     THIS ROUND     14.65        (R9)
//   -> wave-reduce: +3.4us (8 serialized cross-XCD partial loads/lane).
//      KEEP 256-thr reduce (2 loads/lane + LDS tree).
//   -> float2 kernel1: -1.6us (5x dwordx2 per array per 2 pairs = 12 load
//      insts/thread vs 40 scalar; up-front loads force hoisting).
//   Fusion attempts (R4 73us, R7 21us, R8 22us): never re-fuse.
//
// Area(P∩T) via Green's theorem: each clipped edge contributes
// (t1-t0)*cross(A,r); cross(A,r) collapses to per-box constants plus offset
// corrections (components of R(psi)*tc). t0/t1 via Liang-Barsky against an
// AABB in the other box's local frame. Branchless; IEEE inf handles parallel
// edges.

#define BS 256
// 2 chunks x 2 consecutive pairs = 4 pairs/thread -> 512 blocks.
#define CHUNKS 2

__device__ __forceinline__ float lb_delta(float Ax, float Ay,
                                          float irx, float iry,
                                          float hw, float hh)
{
    // Liang-Barsky span of segment A + t*r, t in [0,1], vs |x|<=hw,|y|<=hh
    const float tA = (-hw - Ax) * irx;
    const float tB = ( hw - Ax) * irx;
    const float tC = (-hh - Ay) * iry;
    const float tD = ( hh - Ay) * iry;
    const float tx0 = fminf(tA, tB), tx1 = fmaxf(tA, tB);
    const float ty0 = fminf(tC, tD), ty1 = fmaxf(tC, tD);
    const float t0 = fmaxf(fmaxf(tx0, ty0), 0.0f);   // v_max3
    const float t1 = fminf(fminf(tx1, ty1), 1.0f);   // v_min3
    return fmaxf(t1 - t0, 0.0f);
}

__device__ __forceinline__ float pair_loss_v(float pcx, float pcy, float pw,
                                             float ph, float phi,
                                             float qcx, float qcy, float tw,
                                             float th, float psi)
{
    const float tcx = qcx - pcx, tcy = qcy - pcy;   // pred-centered frame

    const float a1 = 0.5f * pw, b1 = 0.5f * ph;
    const float a2 = 0.5f * tw, b2 = 0.5f * th;

    float sphi, cphi, spsi, cpsi;
    __sincosf(phi, &sphi, &cphi);
    __sincosf(psi, &spsi, &cpsi);
    // delta = psi - phi
    const float cd = cpsi * cphi + spsi * sphi;
    const float sd = spsi * cphi - cpsi * sphi;

    // ---- P edges in T-local frame; clipper AABB (a2,b2) ----
    const float Cx = cpsi * tcx - spsi * tcy;
    const float Cy = spsi * tcx + cpsi * tcy;
    const float Xx = a1 * cd,  Xy = a1 * sd;
    const float Yx = -b1 * sd, Yy = b1 * cd;
    const float i0x = __builtin_amdgcn_rcpf(2.0f * Xx);
    const float i0y = __builtin_amdgcn_rcpf(2.0f * Xy);
    const float i1x = __builtin_amdgcn_rcpf(2.0f * Yx);
    const float i1y = __builtin_amdgcn_rcpf(2.0f * Yy);

    const float dP0 = lb_delta(-Xx - Yx - Cx, -Xy - Yy - Cy,  i0x,  i0y, a2, b2);
    const float dP1 = lb_delta( Xx - Yx - Cx,  Xy - Yy - Cy,  i1x,  i1y, a2, b2);
    const float dP2 = lb_delta( Xx + Yx - Cx,  Xy + Yy - Cy, -i0x, -i0y, a2, b2);
    const float dP3 = lb_delta(-Xx + Yx - Cx, -Xy + Yy - Cy, -i1x, -i1y, a2, b2);
    const float sumP = (dP0 + dP1) + (dP2 + dP3);

    // ---- T edges in P-local frame; clipper AABB (a1,b1) ----
    const float C2x = cphi * tcx - sphi * tcy;
    const float C2y = sphi * tcx + cphi * tcy;
    const float Xpx = a2 * cd,  Xpy = -a2 * sd;
    const float Ypx = b2 * sd,  Ypy = b2 * cd;
    const float j0x = __builtin_amdgcn_rcpf(2.0f * Xpx);
    const float j0y = __builtin_amdgcn_rcpf(2.0f * Xpy);
    const float j1x = __builtin_amdgcn_rcpf(2.0f * Ypx);
    const float j1y = __builtin_amdgcn_rcpf(2.0f * Ypy);

    const float dT0 = lb_delta(C2x - Xpx - Ypx, C2y - Xpy - Ypy,  j0x,  j0y, a1, b1);
    const float dT1 = lb_delta(C2x + Xpx - Ypx, C2y + Xpy - Ypy,  j1x,  j1y, a1, b1);
    const float dT2 = lb_delta(C2x + Xpx + Ypx, C2y + Xpy + Ypy, -j0x, -j0y, a1, b1);
    const float dT3 = lb_delta(C2x - Xpx + Ypx, C2y - Xpy + Ypy, -j1x, -j1y, a1, b1);
    const float sumT = (dT0 + dT1) + (dT2 + dT3);

    float area = a1 * b1 * sumP + a2 * b2 * sumT
               - a2 * Cy * (dT0 - dT2) + b2 * Cx * (dT1 - dT3);
    area = fmaxf(area, 0.0f);

    const float A1 = pw * ph, A2 = tw * th;
    const float iou = fmaxf(area / (A1 + A2 - area + 1e-6f), 1e-6f);
    return -__logf(iou);
}

__global__ __launch_bounds__(BS) void poly_iou_kernel(
    const float* __restrict__ pred, const float* __restrict__ tgt,
    float* __restrict__ block_sums, int n)
{
    const int tid = threadIdx.x;
    const int gthreads = gridDim.x * BS;

    float loss = 0.0f;
#pragma unroll
    for (int ch = 0; ch < CHUNKS; ++ch) {
        const int p0 = 2 * (blockIdx.x * BS + tid + ch * gthreads);
        if (p0 + 1 < n) {
            // two consecutive pairs: 40 contiguous bytes, 8B-aligned
            const float2* pp2 = (const float2*)(pred + (long)p0 * 5);
            const float2* tp2 = (const float2*)(tgt  + (long)p0 * 5);
            const float2 pa = pp2[0], pb = pp2[1], pc = pp2[2],
                         pd = pp2[3], pe = pp2[4];
            const float2 ta = tp2[0], tb = tp2[1], tc = tp2[2],
                         td = tp2[3], te = tp2[4];
            loss += pair_loss_v(pa.x, pa.y, pb.x, pb.y, pc.x,
                                ta.x, ta.y, tb.x, tb.y, tc.x);
            loss += pair_loss_v(pc.y, pd.x, pd.y, pe.x, pe.y,
                                tc.y, td.x, td.y, te.x, te.y);
        } else if (p0 < n) {   // odd tail (not hit for n = 524288)
            const float* pp = pred + (long)p0 * 5;
            const float* tp = tgt  + (long)p0 * 5;
            loss += pair_loss_v(pp[0], pp[1], pp[2], pp[3], pp[4],
                                tp[0], tp[1], tp[2], tp[3], tp[4]);
        }
    }

    // block reduction (wave shuffle + tiny LDS), deterministic
#pragma unroll
    for (int off = 32; off > 0; off >>= 1) loss += __shfl_down(loss, off);
    __shared__ float wsum[BS / 64];
    if ((tid & 63) == 0) wsum[tid >> 6] = loss;
    __syncthreads();
    if (tid == 0) {
        float s = 0.0f;
#pragma unroll
        for (int w = 0; w < BS / 64; ++w) s += wsum[w];
        block_sums[blockIdx.x] = s;
    }
}

// 256-thread reduce: 2 parallel loads/lane + LDS tree (measured best;
// 64-thread version = 8 serialized cross-XCD loads/lane = +3.4us).
__global__ __launch_bounds__(BS) void poly_iou_reduce(
    const float* __restrict__ block_sums, int nblocks,
    float* __restrict__ out, double inv_n)
{
    const int tid = threadIdx.x;
    double s = 0.0;
    for (int i = tid; i < nblocks; i += BS) s += (double)block_sums[i];
#pragma unroll
    for (int off = 32; off > 0; off >>= 1) s += __shfl_down(s, off);
    __shared__ double ws[BS / 64];
    if ((tid & 63) == 0) ws[tid >> 6] = s;
    __syncthreads();
    if (tid == 0) {
        double tot = 0.0;
#pragma unroll
        for (int w = 0; w < BS / 64; ++w) tot += ws[w];
        out[0] = (float)(tot * inv_n);
    }
}

extern "C" void kernel_launch(void* const* d_in, const int* in_sizes, int n_in,
                              void* d_out, int out_size, void* d_ws, size_t ws_size,
                              hipStream_t stream) {
    const float* pred = (const float*)d_in[0];
    const float* tgt  = (const float*)d_in[1];
    float* out = (float*)d_out;
    const int n = in_sizes[0] / 5;
    const int pairs_per_block = BS * CHUNKS * 2;
    const int nblocks = (n + pairs_per_block - 1) / pairs_per_block;
    float* bsums = (float*)d_ws;

    hipLaunchKernelGGL(poly_iou_kernel, dim3(nblocks), dim3(BS), 0, stream,
                       pred, tgt, bsums, n);
    hipLaunchKernelGGL(poly_iou_reduce, dim3(1), dim3(BS), 0, stream,
                       bsums, nblocks, out, 1.0 / (double)n);
}

// Round 13
// 12.327 us; speedup vs baseline: 1.3177x; 1.0037x over previous
//
#include <hip/hip_runtime.h>
#include <math.h>

// PolyIoULoss closed-form, two-kernel structure.
//
// Measured ledger:
//   Fusion (R4 73us, R7 21us, R8 22us): never re-fuse.
//   Reduce tail: 256-thr (2 par loads/lane + LDS tree) beats 64-thr wave
//     (8 serialized cross-XCD loads/lane) by 3.4us.
//   kernel1 loads: scalar 12.6-12.8 (R5/R6/R11) -> float2 12.37 (R12)
//     -> float4 THIS ROUND (10 dwordx4/thread vs 20 dwordx2; 4 consecutive
//     pairs = 80B = 5xfloat4, 16B-aligned since p0%4==0 -> p0*20%80==0).
//
// Area(P∩T) via Green's theorem: each clipped edge contributes
// (t1-t0)*cross(A,r); cross(A,r) collapses to per-box constants plus offset
// corrections (components of R(psi)*tc). t0/t1 via Liang-Barsky against an
// AABB in the other box's local frame. Branchless; IEEE inf handles parallel
// edges. 4 pairs/thread -> 512 blocks (measured-best grid).

#define BS 256

__device__ __forceinline__ float lb_delta(float Ax, float Ay,
                                          float irx, float iry,
                                          float hw, float hh)
{
    // Liang-Barsky span of segment A + t*r, t in [0,1], vs |x|<=hw,|y|<=hh
    const float tA = (-hw - Ax) * irx;
    const float tB = ( hw - Ax) * irx;
    const float tC = (-hh - Ay) * iry;
    const float tD = ( hh - Ay) * iry;
    const float tx0 = fminf(tA, tB), tx1 = fmaxf(tA, tB);
    const float ty0 = fminf(tC, tD), ty1 = fmaxf(tC, tD);
    const float t0 = fmaxf(fmaxf(tx0, ty0), 0.0f);   // v_max3
    const float t1 = fminf(fminf(tx1, ty1), 1.0f);   // v_min3
    return fmaxf(t1 - t0, 0.0f);
}

__device__ __forceinline__ float pair_loss_v(float pcx, float pcy, float pw,
                                             float ph, float phi,
                                             float qcx, float qcy, float tw,
                                             float th, float psi)
{
    const float tcx = qcx - pcx, tcy = qcy - pcy;   // pred-centered frame

    const float a1 = 0.5f * pw, b1 = 0.5f * ph;
    const float a2 = 0.5f * tw, b2 = 0.5f * th;

    float sphi, cphi, spsi, cpsi;
    __sincosf(phi, &sphi, &cphi);
    __sincosf(psi, &spsi, &cpsi);
    // delta = psi - phi
    const float cd = cpsi * cphi + spsi * sphi;
    const float sd = spsi * cphi - cpsi * sphi;

    // ---- P edges in T-local frame; clipper AABB (a2,b2) ----
    const float Cx = cpsi * tcx - spsi * tcy;
    const float Cy = spsi * tcx + cpsi * tcy;
    const float Xx = a1 * cd,  Xy = a1 * sd;
    const float Yx = -b1 * sd, Yy = b1 * cd;
    const float i0x = __builtin_amdgcn_rcpf(2.0f * Xx);
    const float i0y = __builtin_amdgcn_rcpf(2.0f * Xy);
    const float i1x = __builtin_amdgcn_rcpf(2.0f * Yx);
    const float i1y = __builtin_amdgcn_rcpf(2.0f * Yy);

    const float dP0 = lb_delta(-Xx - Yx - Cx, -Xy - Yy - Cy,  i0x,  i0y, a2, b2);
    const float dP1 = lb_delta( Xx - Yx - Cx,  Xy - Yy - Cy,  i1x,  i1y, a2, b2);
    const float dP2 = lb_delta( Xx + Yx - Cx,  Xy + Yy - Cy, -i0x, -i0y, a2, b2);
    const float dP3 = lb_delta(-Xx + Yx - Cx, -Xy + Yy - Cy, -i1x, -i1y, a2, b2);
    const float sumP = (dP0 + dP1) + (dP2 + dP3);

    // ---- T edges in P-local frame; clipper AABB (a1,b1) ----
    const float C2x = cphi * tcx - sphi * tcy;
    const float C2y = sphi * tcx + cphi * tcy;
    const float Xpx = a2 * cd,  Xpy = -a2 * sd;
    const float Ypx = b2 * sd,  Ypy = b2 * cd;
    const float j0x = __builtin_amdgcn_rcpf(2.0f * Xpx);
    const float j0y = __builtin_amdgcn_rcpf(2.0f * Xpy);
    const float j1x = __builtin_amdgcn_rcpf(2.0f * Ypx);
    const float j1y = __builtin_amdgcn_rcpf(2.0f * Ypy);

    const float dT0 = lb_delta(C2x - Xpx - Ypx, C2y - Xpy - Ypy,  j0x,  j0y, a1, b1);
    const float dT1 = lb_delta(C2x + Xpx - Ypx, C2y + Xpy - Ypy,  j1x,  j1y, a1, b1);
    const float dT2 = lb_delta(C2x + Xpx + Ypx, C2y + Xpy + Ypy, -j0x, -j0y, a1, b1);
    const float dT3 = lb_delta(C2x - Xpx + Ypx, C2y - Xpy + Ypy, -j1x, -j1y, a1, b1);
    const float sumT = (dT0 + dT1) + (dT2 + dT3);

    float area = a1 * b1 * sumP + a2 * b2 * sumT
               - a2 * Cy * (dT0 - dT2) + b2 * Cx * (dT1 - dT3);
    area = fmaxf(area, 0.0f);

    const float A1 = pw * ph, A2 = tw * th;
    const float iou = fmaxf(area / (A1 + A2 - area + 1e-6f), 1e-6f);
    return -__logf(iou);
}

__global__ __launch_bounds__(BS) void poly_iou_kernel(
    const float* __restrict__ pred, const float* __restrict__ tgt,
    float* __restrict__ block_sums, int n)
{
    const int tid = threadIdx.x;

    float loss = 0.0f;
    const int p0 = 4 * (blockIdx.x * BS + tid);
    if (p0 + 3 < n) {
        // four consecutive pairs: 80 contiguous bytes = 5 x float4 per array
        const float4* pp4 = (const float4*)(pred + (long)p0 * 5);
        const float4* tp4 = (const float4*)(tgt  + (long)p0 * 5);
        const float4 f0 = pp4[0], f1 = pp4[1], f2 = pp4[2],
                     f3 = pp4[3], f4 = pp4[4];
        const float4 g0 = tp4[0], g1 = tp4[1], g2 = tp4[2],
                     g3 = tp4[3], g4 = tp4[4];
        loss += pair_loss_v(f0.x, f0.y, f0.z, f0.w, f1.x,
                            g0.x, g0.y, g0.z, g0.w, g1.x);
        loss += pair_loss_v(f1.y, f1.z, f1.w, f2.x, f2.y,
                            g1.y, g1.z, g1.w, g2.x, g2.y);
        loss += pair_loss_v(f2.z, f2.w, f3.x, f3.y, f3.z,
                            g2.z, g2.w, g3.x, g3.y, g3.z);
        loss += pair_loss_v(f3.w, f4.x, f4.y, f4.z, f4.w,
                            g3.w, g4.x, g4.y, g4.z, g4.w);
    } else {
        for (int p = p0; p < n; ++p) {   // tail (not hit for n = 524288)
            const float* pp = pred + (long)p * 5;
            const float* tp = tgt  + (long)p * 5;
            loss += pair_loss_v(pp[0], pp[1], pp[2], pp[3], pp[4],
                                tp[0], tp[1], tp[2], tp[3], tp[4]);
        }
    }

    // block reduction (wave shuffle + tiny LDS), deterministic
#pragma unroll
    for (int off = 32; off > 0; off >>= 1) loss += __shfl_down(loss, off);
    __shared__ float wsum[BS / 64];
    if ((tid & 63) == 0) wsum[tid >> 6] = loss;
    __syncthreads();
    if (tid == 0) {
        float s = 0.0f;
#pragma unroll
        for (int w = 0; w < BS / 64; ++w) s += wsum[w];
        block_sums[blockIdx.x] = s;
    }
}

// 256-thread reduce: 2 parallel loads/lane + LDS tree (measured best;
// 64-thread version = 8 serialized cross-XCD loads/lane = +3.4us).
__global__ __launch_bounds__(BS) void poly_iou_reduce(
    const float* __restrict__ block_sums, int nblocks,
    float* __restrict__ out, double inv_n)
{
    const int tid = threadIdx.x;
    double s = 0.0;
    for (int i = tid; i < nblocks; i += BS) s += (double)block_sums[i];
#pragma unroll
    for (int off = 32; off > 0; off >>= 1) s += __shfl_down(s, off);
    __shared__ double ws[BS / 64];
    if ((tid & 63) == 0) ws[tid >> 6] = s;
    __syncthreads();
    if (tid == 0) {
        double tot = 0.0;
#pragma unroll
        for (int w = 0; w < BS / 64; ++w) tot += ws[w];
        out[0] = (float)(tot * inv_n);
    }
}

extern "C" void kernel_launch(void* const* d_in, const int* in_sizes, int n_in,
                              void* d_out, int out_size, void* d_ws, size_t ws_size,
                              hipStream_t stream) {
    const float* pred = (const float*)d_in[0];
    const float* tgt  = (const float*)d_in[1];
    float* out = (float*)d_out;
    const int n = in_sizes[0] / 5;
    const int pairs_per_block = BS * 4;
    const int nblocks = (n + pairs_per_block - 1) / pairs_per_block;
    float* bsums = (float*)d_ws;

    hipLaunchKernelGGL(poly_iou_kernel, dim3(nblocks), dim3(BS), 0, stream,
                       pred, tgt, bsums, n);
    hipLaunchKernelGGL(poly_iou_reduce, dim3(1), dim3(BS), 0, stream,
                       bsums, nblocks, out, 1.0 / (double)n);
}